// Round 6
// baseline (203.442 us; speedup 1.0000x reference)
//
#include <hip/hip_runtime.h>
#include <stdint.h>

#define BATCH 2
#define DIM 1024
#define NSEQ 2048
#define HEADS 16
#define DHEAD 64
#define INNER 1024
#define O3 3072

typedef __attribute__((ext_vector_type(8))) short bf16x8;
typedef __attribute__((ext_vector_type(4))) float f32x4;

typedef __attribute__((address_space(3))) unsigned int* as3u;
typedef const __attribute__((address_space(1))) unsigned int* as1u;

__device__ __forceinline__ short f2bf(float f) {
  unsigned int u = __builtin_bit_cast(unsigned int, f);
  unsigned int r = (u + 0x7fffu + ((u >> 16) & 1u)) >> 16;
  return (short)(unsigned short)r;
}
__device__ __forceinline__ float bf2f(short s) {
  unsigned int u = ((unsigned int)(unsigned short)s) << 16;
  return __builtin_bit_cast(float, u);
}
__device__ __forceinline__ void gload16(const short* g, short* l) {
  __builtin_amdgcn_global_load_lds((as1u)(const void*)g, (as3u)(void*)l, 16, 0, 0);
}

// ---------------- cast weights f32 -> bf16 ----------------
__global__ void k_cast_weights(const float* __restrict__ wq, const float* __restrict__ wo,
                               short* __restrict__ wq_bf, short* __restrict__ wo_bf) {
  int i = blockIdx.x * 256 + threadIdx.x;   // each thread: 4 elems
  const int NQ4 = O3 * DIM / 4;             // 786432
  const float4* src;
  unsigned int* dst;
  int j;
  if (i < NQ4) { src = (const float4*)wq; dst = (unsigned int*)wq_bf; j = i; }
  else         { src = (const float4*)wo; dst = (unsigned int*)wo_bf; j = i - NQ4; }
  float4 v = src[j];
  unsigned int lo = ((unsigned int)(unsigned short)f2bf(v.y) << 16) | (unsigned short)f2bf(v.x);
  unsigned int hi = ((unsigned int)(unsigned short)f2bf(v.w) << 16) | (unsigned short)f2bf(v.z);
  dst[j * 2] = lo;
  dst[j * 2 + 1] = hi;
}

// ---------------- rope table [n][64] f32: cols 0..31 = cos, 32..63 = sin ----------------
__global__ void k_rope_table(float* __restrict__ tab) {
  int i = blockIdx.x * 256 + threadIdx.x;   // 2048*32 = 65536
  int n = i >> 5, d = i & 31;
  float inv = powf(10000.0f, -(float)d * (1.0f / 32.0f));
  float ang = inv * (4.0f * (float)n);      // t = n * (8192/2048)
  float s, c;
  sincosf(ang, &s, &c);
  tab[n * 64 + d] = c;
  tab[n * 64 + 32 + d] = s;
}

// ---------------- x [b][d][n] f32 -> Xt [b][n][d] bf16 ----------------
__global__ void k_transpose_x(const float* __restrict__ x, short* __restrict__ xt) {
  __shared__ short tile[64 * 65];
  int nt = blockIdx.x, dt = blockIdx.y, b = blockIdx.z;
  int t = threadIdx.x;
  int tc = t & 63, tr = t >> 6;
  const float* xp = x + ((size_t)b * DIM + dt * 64) * NSEQ + nt * 64;
  #pragma unroll
  for (int r = 0; r < 16; ++r) {
    int d = r * 4 + tr;
    tile[d * 65 + tc] = f2bf(xp[(size_t)d * NSEQ + tc]);
  }
  __syncthreads();
  short* op = xt + ((size_t)b * NSEQ + nt * 64) * DIM + dt * 64;
  #pragma unroll
  for (int r = 0; r < 16; ++r) {
    int n = r * 4 + tr;
    op[(size_t)n * DIM + tc] = tile[tc * 65 + n];
  }
}

// ---------------- GEMM (2-phase dbuf, global_load_lds w16): C[M][2048] = A[M][K] * B^T ----------------
// B is [2048 rows][K] k-fastest. Grid: 1D NB = 16 * (M/128) * BATCH, XCD-swizzled.
template <int EPI>
__global__ __launch_bounds__(256) void k_gemm(const short* __restrict__ A,
                                              const short* __restrict__ Bmat,
                                              short* __restrict__ Cbf, float* __restrict__ Cf,
                                              const float* __restrict__ bias, int M, int K) {
  __shared__ __align__(16) short lds_a[2][128 * 32];
  __shared__ __align__(16) short lds_b[2][128 * 32];
  const int t = threadIdx.x;
  const int lane = t & 63, w = t >> 6;
  const int lr = lane & 15, lg = lane >> 4;
  // XCD-chunked bijective swizzle (gridDim.x % 8 == 0)
  const int cpx = gridDim.x >> 3;
  const int swz = (blockIdx.x & 7) * cpx + (blockIdx.x >> 3);
  const int mtiles = M >> 7;
  const int n0 = (swz & 15) * 128;
  const int rest = swz >> 4;
  const int m0 = (rest % mtiles) * 128;
  const int bz = rest / mtiles;

  const short* Bp = Bmat + (size_t)bz * NSEQ * K;
  // staging: per wave 2 instrs per operand; lane l -> row 32w+16q+(l>>2), slot l&3
  const short* gA = A + (size_t)(m0 + 32 * w + (lane >> 2)) * K + (lane & 3) * 8;
  const short* gB = Bp + (size_t)(n0 + 32 * w + (lane >> 2)) * K + (lane & 3) * 8;
  const int wm = (w >> 1) * 64, wn = (w & 1) * 64;

  auto STAGE = [&](int buf, int kk) {
    const short* ga = gA + kk * 32;
    const short* gb = gB + kk * 32;
    gload16(ga, &lds_a[buf][(32 * w) * 32]);
    gload16(ga + (size_t)16 * K, &lds_a[buf][(32 * w + 16) * 32]);
    gload16(gb, &lds_b[buf][(32 * w) * 32]);
    gload16(gb + (size_t)16 * K, &lds_b[buf][(32 * w + 16) * 32]);
  };

  f32x4 acc[4][4];
  const f32x4 zf = {0.f, 0.f, 0.f, 0.f};
  #pragma unroll
  for (int i = 0; i < 4; ++i)
    #pragma unroll
    for (int j = 0; j < 4; ++j) acc[i][j] = zf;

  STAGE(0, 0);
  asm volatile("s_waitcnt vmcnt(0)" ::: "memory");
  __syncthreads();

  const int nkt = K >> 5;
  int cur = 0;
  for (int kt = 0; kt < nkt; ++kt) {
    if (kt + 1 < nkt) STAGE(cur ^ 1, kt + 1);
    bf16x8 af[4], bfr[4];
    #pragma unroll
    for (int mi = 0; mi < 4; ++mi)
      af[mi] = *(const bf16x8*)&lds_a[cur][(wm + mi * 16 + lr) * 32 + lg * 8];
    #pragma unroll
    for (int nj = 0; nj < 4; ++nj)
      bfr[nj] = *(const bf16x8*)&lds_b[cur][(wn + nj * 16 + lr) * 32 + lg * 8];
    __builtin_amdgcn_s_setprio(1);
    #pragma unroll
    for (int mi = 0; mi < 4; ++mi)
      #pragma unroll
      for (int nj = 0; nj < 4; ++nj)
        acc[mi][nj] = __builtin_amdgcn_mfma_f32_16x16x32_bf16(af[mi], bfr[nj], acc[mi][nj], 0, 0, 0);
    __builtin_amdgcn_s_setprio(0);
    asm volatile("s_waitcnt vmcnt(0)" ::: "memory");
    __syncthreads();
    cur ^= 1;
  }

  if (EPI == 0) {
    short* Cp = Cbf + (size_t)bz * M * NSEQ;
    #pragma unroll
    for (int mi = 0; mi < 4; ++mi)
      #pragma unroll
      for (int nj = 0; nj < 4; ++nj)
        #pragma unroll
        for (int r = 0; r < 4; ++r) {
          int row = m0 + wm + mi * 16 + lg * 4 + r;
          int col = n0 + wn + nj * 16 + lr;
          Cp[(size_t)row * NSEQ + col] = f2bf(acc[mi][nj][r]);
        }
  } else {
    float* Cp = Cf + (size_t)bz * M * NSEQ;
    #pragma unroll
    for (int mi = 0; mi < 4; ++mi)
      #pragma unroll
      for (int nj = 0; nj < 4; ++nj)
        #pragma unroll
        for (int r = 0; r < 4; ++r) {
          int row = m0 + wm + mi * 16 + lg * 4 + r;
          int col = n0 + wn + nj * 16 + lr;
          Cp[(size_t)row * NSEQ + col] = acc[mi][nj][r] + bias[row];
        }
  }
}

// ---------------- RoPE for K only: qkv rows 1024..2047 -> Kt [b][h][n][64] bf16 ----------------
__global__ void k_ropeK(const short* __restrict__ qkv, const float* __restrict__ tab,
                        short* __restrict__ Kt) {
  __shared__ short lt[64 * 64];   // [n][d] swizzled: elem d stored at d ^ ((n&7)<<3)
  const int t = threadIdx.x;
  const int nc = blockIdx.x, h = blockIdx.y, b = blockIdx.z;
  const short* src = qkv + ((size_t)(b * O3 + INNER + h * 64)) * NSEQ + nc * 64;
  {
    int dl = t >> 2, q4 = t & 3;
    #pragma unroll
    for (int v = 0; v < 2; ++v) {
      bf16x8 x = *(const bf16x8*)(src + (size_t)dl * NSEQ + q4 * 16 + v * 8);
      #pragma unroll
      for (int e = 0; e < 8; ++e) {
        int n = q4 * 16 + v * 8 + e;
        lt[n * 64 + (dl ^ ((n & 7) << 3))] = x[e];
      }
    }
  }
  __syncthreads();
  const int dseg = t & 7;
  #pragma unroll
  for (int itn = 0; itn < 2; ++itn) {
    int n = (t >> 3) + itn * 32;
    int gn = nc * 64 + n;
    bf16x8 v0 = *(const bf16x8*)&lt[n * 64 + ((dseg ^ (n & 7)) << 3)];
    bf16x8 vp = *(const bf16x8*)&lt[n * 64 + (((dseg ^ 4) ^ (n & 7)) << 3)];
    const float* tb = tab + (size_t)gn * 64 + (dseg & 3) * 8;
    float sgn = (dseg < 4) ? -1.0f : 1.0f;
    bf16x8 outv;
    #pragma unroll
    for (int e = 0; e < 8; ++e) {
      float c = tb[e], s = tb[32 + e];
      outv[e] = f2bf(bf2f(v0[e]) * c + sgn * bf2f(vp[e]) * s);
    }
    *(bf16x8*)(Kt + (((size_t)(b * HEADS + h)) * NSEQ + gn) * 64 + dseg * 8) = outv;
  }
}

// ---------------- flash attention (fixed-shift softmax, sum via ones-MFMA) ----------------
// 256 thr = 4 waves; wave owns 32 q-rows (2 sub-tiles of 16); block = 128 q-rows.
// P roundtrip: round-3-verified swizzled [i][j] LDS write + ds_read_b128.
__global__ __launch_bounds__(256) void k_attn(const short* __restrict__ qkv,
                                              const short* __restrict__ Kt,
                                              const float* __restrict__ tab,
                                              short* __restrict__ AOt) {
  __shared__ __align__(16) short smem[16384];   // 32 KiB
  const int t = threadIdx.x, lane = t & 63, w = t >> 6;
  const int lr = lane & 15, lg = lane >> 4;
  const int L = ((blockIdx.x & 7) << 6) | (blockIdx.x >> 3);
  const int it = L & 15, h = (L >> 4) & 15, b = L >> 8;
  const int i0 = it * 128;

  // ---- Q stage: qkv rows h*64..+63 (o-major) -> smem[0..8192) as [64 d][128 n] swizzled
  const short* Qsrc = qkv + ((size_t)(b * O3 + h * 64)) * NSEQ;
  {
    int dl = t >> 2, q4 = t & 3;
    const short* gq = Qsrc + (size_t)dl * NSEQ + i0 + q4 * 32;
    #pragma unroll
    for (int kk = 0; kk < 4; ++kk) {
      bf16x8 x = *(const bf16x8*)(gq + kk * 8);
      *(bf16x8*)&smem[dl * 128 + (((q4 * 4 + kk) ^ (dl & 7)) << 3)] = x;
    }
  }
  __syncthreads();
  // ---- gather + RoPE + 0.125 scale -> aq[sub][part]
  bf16x8 aq[2][2];
  #pragma unroll
  for (int sub = 0; sub < 2; ++sub) {
    int il = w * 32 + sub * 16 + lr;
    int gn = i0 + il;
    float q0[8], q1[8];
    #pragma unroll
    for (int e = 0; e < 8; ++e) {
      int d0 = lg * 8 + e;
      int sw = (((il >> 3) ^ e) << 3) + (il & 7);
      q0[e] = bf2f(smem[d0 * 128 + sw]);
      q1[e] = bf2f(smem[(d0 + 32) * 128 + sw]);
    }
    const float* tb = tab + (size_t)gn * 64 + lg * 8;
    bf16x8 a0, a1;
    #pragma unroll
    for (int e = 0; e < 8; ++e) {
      float c = tb[e], s = tb[32 + e];
      a0[e] = f2bf((q0[e] * c - q1[e] * s) * 0.125f);
      a1[e] = f2bf((q1[e] * c + q0[e] * s) * 0.125f);
    }
    aq[sub][0] = a0; aq[sub][1] = a1;
  }

  const short* Kh = Kt + ((size_t)(b * HEADS + h)) * NSEQ * 64;
  const short* Vh = qkv + ((size_t)(b * O3 + 2 * INNER + h * 64)) * NSEQ;
  short* lds_k = smem;                       // [64 j][64 d] swizzled
  short* lds_v = smem + 4096;                // [64 d][64 j] swizzled
  short* lds_p = smem + 8192 + w * 2048;     // per-wave: 2 subs x [16 i][64 j] swizzled

  f32x4 o_acc[2][4];
  f32x4 sum_acc[2];
  const f32x4 zf = {0.f, 0.f, 0.f, 0.f};
  const f32x4 c10 = {-10.f, -10.f, -10.f, -10.f};
  #pragma unroll
  for (int sub = 0; sub < 2; ++sub) {
    sum_acc[sub] = zf;
    #pragma unroll
    for (int dg = 0; dg < 4; ++dg) o_acc[sub][dg] = zf;
  }
  bf16x8 ones;
  #pragma unroll
  for (int e = 0; e < 8; ++e) ones[e] = (short)0x3F80;

  const int srow = t >> 3, sslot = t & 7;
  const short* gk0 = Kh + (size_t)srow * 64 + sslot * 8;
  const short* gk1 = gk0 + 32 * 64;
  const short* gv0 = Vh + (size_t)srow * NSEQ + sslot * 8;
  const short* gv1 = gv0 + (size_t)32 * NSEQ;
  const int sk0 = srow * 64 + ((sslot ^ (srow & 7)) << 3);

  bf16x8 rk0 = *(const bf16x8*)gk0, rk1 = *(const bf16x8*)gk1;
  bf16x8 rv0 = *(const bf16x8*)gv0, rv1 = *(const bf16x8*)gv1;

  for (int jt = 0; jt < NSEQ / 64; ++jt) {
    __syncthreads();
    *(bf16x8*)&lds_k[sk0] = rk0; *(bf16x8*)&lds_k[sk0 + 2048] = rk1;
    *(bf16x8*)&lds_v[sk0] = rv0; *(bf16x8*)&lds_v[sk0 + 2048] = rv1;
    __syncthreads();
    if (jt + 1 < NSEQ / 64) {
      gk0 += 64 * 64; gk1 += 64 * 64; gv0 += 64; gv1 += 64;
      rk0 = *(const bf16x8*)gk0; rk1 = *(const bf16x8*)gk1;
      rv0 = *(const bf16x8*)gv0; rv1 = *(const bf16x8*)gv1;
    }
    // ---- S = Q K^T - 10 (both sub-tiles share K fragments)
    f32x4 sA[4], sB[4];
    __builtin_amdgcn_s_setprio(1);
    #pragma unroll
    for (int jg = 0; jg < 4; ++jg) {
      int row = jg * 16 + lr;
      bf16x8 bk0 = *(const bf16x8*)&lds_k[row * 64 + ((lg ^ (row & 7)) << 3)];
      bf16x8 bk1 = *(const bf16x8*)&lds_k[row * 64 + (((4 + lg) ^ (row & 7)) << 3)];
      sA[jg] = __builtin_amdgcn_mfma_f32_16x16x32_bf16(aq[0][0], bk0, c10, 0, 0, 0);
      sA[jg] = __builtin_amdgcn_mfma_f32_16x16x32_bf16(aq[0][1], bk1, sA[jg], 0, 0, 0);
      sB[jg] = __builtin_amdgcn_mfma_f32_16x16x32_bf16(aq[1][0], bk0, c10, 0, 0, 0);
      sB[jg] = __builtin_amdgcn_mfma_f32_16x16x32_bf16(aq[1][1], bk1, sB[jg], 0, 0, 0);
    }
    __builtin_amdgcn_s_setprio(0);
    // ---- per sub: p = exp(s) -> LDS (bf16, swizzled [i][j]), then sum via ones-MFMA + PV
    bf16x8 bv[2][4];
    #pragma unroll
    for (int sub = 0; sub < 2; ++sub) {
      short* pb = lds_p + sub * 1024;
      #pragma unroll
      for (int jg = 0; jg < 4; ++jg)
        #pragma unroll
        for (int r = 0; r < 4; ++r) {
          float p = __expf(sub ? sB[jg][r] : sA[jg][r]);
          int ir = 4 * lg + r;
          pb[ir * 64 + (((jg * 2 + (lr >> 3)) ^ (ir & 7)) << 3) + (lr & 7)] = f2bf(p);
        }
      #pragma unroll
      for (int jj = 0; jj < 2; ++jj) {
        bf16x8 ap = *(const bf16x8*)&pb[lr * 64 + (((jj * 4 + lg) ^ (lr & 7)) << 3)];
        sum_acc[sub] = __builtin_amdgcn_mfma_f32_16x16x32_bf16(ones, ap, sum_acc[sub], 0, 0, 0);
        if (sub == 0) {
          #pragma unroll
          for (int dg = 0; dg < 4; ++dg) {
            int row = dg * 16 + lr;
            bv[jj][dg] = *(const bf16x8*)&lds_v[row * 64 + (((jj * 4 + lg) ^ (row & 7)) << 3)];
          }
        }
        __builtin_amdgcn_s_setprio(1);
        #pragma unroll
        for (int dg = 0; dg < 4; ++dg)
          o_acc[sub][dg] = __builtin_amdgcn_mfma_f32_16x16x32_bf16(ap, bv[jj][dg], o_acc[sub][dg], 0, 0, 0);
        __builtin_amdgcn_s_setprio(0);
      }
    }
  }
  // ---- epilogue: O /= l ; AOt[b][n][h*64+d]
  short* Op = AOt + (size_t)b * NSEQ * INNER;
  #pragma unroll
  for (int sub = 0; sub < 2; ++sub) {
    float l0 = sum_acc[sub][0];
    float inv[4];
    #pragma unroll
    for (int r = 0; r < 4; ++r) inv[r] = 1.0f / __shfl(l0, 4 * lg + r, 64);
    #pragma unroll
    for (int dg = 0; dg < 4; ++dg)
      #pragma unroll
      for (int r = 0; r < 4; ++r) {
        int n = i0 + w * 32 + sub * 16 + 4 * lg + r;
        int c = h * 64 + dg * 16 + lr;
        Op[(size_t)n * INNER + c] = f2bf(o_acc[sub][dg][r] * inv[r]);
      }
  }
}

// ---------------- launch ----------------
extern "C" void kernel_launch(void* const* d_in, const int* in_sizes, int n_in,
                              void* d_out, int out_size, void* d_ws, size_t ws_size,
                              hipStream_t stream) {
  const float* x = (const float*)d_in[0];
  const float* w_qkv = (const float*)d_in[1];
  const float* w_out = (const float*)d_in[2];
  const float* b_out = (const float*)d_in[3];
  float* out = (float*)d_out;
  char* ws = (char*)d_ws;
  short* wq_bf = (short*)(ws + 0);          //  6,291,456
  short* wo_bf = (short*)(ws + 6291456);    //  2,097,152
  short* Xt    = (short*)(ws + 8388608);    //  8,388,608  [b][n][d] bf16
  float* tab   = (float*)(ws + 16777216);   //    524,288  [2048 n][64] cos|sin
  short* qkv   = (short*)(ws + 17301504);   // 25,165,824  [b][3072][n] bf16
  short* Kt    = (short*)(ws + 42467328);   //  8,388,608  [b][h][n][64] bf16 (rope'd)
  short* AOt   = (short*)(ws + 50855936);   //  8,388,608  [b][n][1024] bf16

  k_cast_weights<<<4096, 256, 0, stream>>>(w_qkv, w_out, wq_bf, wo_bf);
  k_rope_table<<<256, 256, 0, stream>>>(tab);
  k_transpose_x<<<dim3(32, 16, BATCH), 256, 0, stream>>>(x, Xt);
  k_gemm<0><<<768, 256, 0, stream>>>(wq_bf, Xt, qkv, nullptr, nullptr, O3, DIM);
  k_ropeK<<<dim3(32, 16, BATCH), 256, 0, stream>>>(qkv, tab, Kt);
  k_attn<<<512, 256, 0, stream>>>(qkv, Kt, tab, AOt);
  k_gemm<1><<<256, 256, 0, stream>>>(wo_bf, AOt, nullptr, out, b_out, INNER, INNER);
}

// Round 7
// 199.759 us; speedup vs baseline: 1.0184x; 1.0184x over previous
//
#include <hip/hip_runtime.h>
#include <stdint.h>

#define BATCH 2
#define DIM 1024
#define NSEQ 2048
#define HEADS 16
#define DHEAD 64
#define INNER 1024
#define O3 3072

typedef __attribute__((ext_vector_type(8))) short bf16x8;
typedef __attribute__((ext_vector_type(4))) float f32x4;

typedef __attribute__((address_space(3))) unsigned int* as3u;
typedef const __attribute__((address_space(1))) unsigned int* as1u;

__device__ __forceinline__ short f2bf(float f) {
  unsigned int u = __builtin_bit_cast(unsigned int, f);
  unsigned int r = (u + 0x7fffu + ((u >> 16) & 1u)) >> 16;
  return (short)(unsigned short)r;
}
__device__ __forceinline__ float bf2f(short s) {
  unsigned int u = ((unsigned int)(unsigned short)s) << 16;
  return __builtin_bit_cast(float, u);
}
__device__ __forceinline__ void gload16(const short* g, short* l) {
  __builtin_amdgcn_global_load_lds((as1u)(const void*)g, (as3u)(void*)l, 16, 0, 0);
}

// ---------------- cast weights f32 -> bf16 ----------------
__global__ void k_cast_weights(const float* __restrict__ wq, const float* __restrict__ wo,
                               short* __restrict__ wq_bf, short* __restrict__ wo_bf) {
  int i = blockIdx.x * 256 + threadIdx.x;   // each thread: 4 elems
  const int NQ4 = O3 * DIM / 4;             // 786432
  const float4* src;
  unsigned int* dst;
  int j;
  if (i < NQ4) { src = (const float4*)wq; dst = (unsigned int*)wq_bf; j = i; }
  else         { src = (const float4*)wo; dst = (unsigned int*)wo_bf; j = i - NQ4; }
  float4 v = src[j];
  unsigned int lo = ((unsigned int)(unsigned short)f2bf(v.y) << 16) | (unsigned short)f2bf(v.x);
  unsigned int hi = ((unsigned int)(unsigned short)f2bf(v.w) << 16) | (unsigned short)f2bf(v.z);
  dst[j * 2] = lo;
  dst[j * 2 + 1] = hi;
}

// ---------------- rope table [n][64] f32: cols 0..31 = cos, 32..63 = sin ----------------
__global__ void k_rope_table(float* __restrict__ tab) {
  int i = blockIdx.x * 256 + threadIdx.x;   // 2048*32 = 65536
  int n = i >> 5, d = i & 31;
  float inv = powf(10000.0f, -(float)d * (1.0f / 32.0f));
  float ang = inv * (4.0f * (float)n);      // t = n * (8192/2048)
  float s, c;
  sincosf(ang, &s, &c);
  tab[n * 64 + d] = c;
  tab[n * 64 + 32 + d] = s;
}

// ---------------- x [b][d][n] f32 -> Xt [b][n][d] bf16 ----------------
__global__ void k_transpose_x(const float* __restrict__ x, short* __restrict__ xt) {
  __shared__ short tile[64 * 65];
  int nt = blockIdx.x, dt = blockIdx.y, b = blockIdx.z;
  int t = threadIdx.x;
  int tc = t & 63, tr = t >> 6;
  const float* xp = x + ((size_t)b * DIM + dt * 64) * NSEQ + nt * 64;
  #pragma unroll
  for (int r = 0; r < 16; ++r) {
    int d = r * 4 + tr;
    tile[d * 65 + tc] = f2bf(xp[(size_t)d * NSEQ + tc]);
  }
  __syncthreads();
  short* op = xt + ((size_t)b * NSEQ + nt * 64) * DIM + dt * 64;
  #pragma unroll
  for (int r = 0; r < 16; ++r) {
    int n = r * 4 + tr;
    op[(size_t)n * DIM + tc] = tile[tc * 65 + n];
  }
}

// ---------------- GEMM (2-phase dbuf, global_load_lds w16): C[M][2048] = A[M][K] * B^T ----------------
// B is [2048 rows][K] k-fastest. Grid: 1D NB = 16 * (M/BM) * BATCH, XCD-swizzled.
template <int EPI, int BM>
__global__ __launch_bounds__(256) void k_gemm(const short* __restrict__ A,
                                              const short* __restrict__ Bmat,
                                              short* __restrict__ Cbf, float* __restrict__ Cf,
                                              const float* __restrict__ bias, int M, int K) {
  constexpr int MI = BM / 32;               // m-fragments per wave (128->4, 64->2)
  __shared__ __align__(16) short lds_a[2][BM * 32];
  __shared__ __align__(16) short lds_b[2][128 * 32];
  const int t = threadIdx.x;
  const int lane = t & 63, w = t >> 6;
  const int lr = lane & 15, lg = lane >> 4;
  // XCD-chunked bijective swizzle (gridDim.x % 8 == 0)
  const int cpx = gridDim.x >> 3;
  const int swz = (blockIdx.x & 7) * cpx + (blockIdx.x >> 3);
  const int mtiles = M / BM;
  const int n0 = (swz & 15) * 128;
  const int rest = swz >> 4;
  const int m0 = (rest % mtiles) * BM;
  const int bz = rest / mtiles;

  const short* Bp = Bmat + (size_t)bz * NSEQ * K;
  const int arow0 = (BM == 128 ? 32 * w : 16 * w);
  const short* gA = A + (size_t)(m0 + arow0 + (lane >> 2)) * K + (lane & 3) * 8;
  const short* gB = Bp + (size_t)(n0 + 32 * w + (lane >> 2)) * K + (lane & 3) * 8;
  const int wm = (w >> 1) * (BM / 2), wn = (w & 1) * 64;

  auto STAGE = [&](int buf, int kk) {
    const short* ga = gA + kk * 32;
    const short* gb = gB + kk * 32;
    gload16(ga, &lds_a[buf][arow0 * 32]);
    if (BM == 128) gload16(ga + (size_t)16 * K, &lds_a[buf][(arow0 + 16) * 32]);
    gload16(gb, &lds_b[buf][(32 * w) * 32]);
    gload16(gb + (size_t)16 * K, &lds_b[buf][(32 * w + 16) * 32]);
  };

  f32x4 acc[MI][4];
  const f32x4 zf = {0.f, 0.f, 0.f, 0.f};
  #pragma unroll
  for (int i = 0; i < MI; ++i)
    #pragma unroll
    for (int j = 0; j < 4; ++j) acc[i][j] = zf;

  STAGE(0, 0);
  asm volatile("s_waitcnt vmcnt(0)" ::: "memory");
  __syncthreads();

  const int nkt = K >> 5;
  int cur = 0;
  for (int kt = 0; kt < nkt; ++kt) {
    if (kt + 1 < nkt) STAGE(cur ^ 1, kt + 1);
    bf16x8 af[MI], bfr[4];
    #pragma unroll
    for (int mi = 0; mi < MI; ++mi)
      af[mi] = *(const bf16x8*)&lds_a[cur][(wm + mi * 16 + lr) * 32 + lg * 8];
    #pragma unroll
    for (int nj = 0; nj < 4; ++nj)
      bfr[nj] = *(const bf16x8*)&lds_b[cur][(wn + nj * 16 + lr) * 32 + lg * 8];
    __builtin_amdgcn_s_setprio(1);
    #pragma unroll
    for (int mi = 0; mi < MI; ++mi)
      #pragma unroll
      for (int nj = 0; nj < 4; ++nj)
        acc[mi][nj] = __builtin_amdgcn_mfma_f32_16x16x32_bf16(af[mi], bfr[nj], acc[mi][nj], 0, 0, 0);
    __builtin_amdgcn_s_setprio(0);
    asm volatile("s_waitcnt vmcnt(0)" ::: "memory");
    __syncthreads();
    cur ^= 1;
  }

  if (EPI == 0) {
    short* Cp = Cbf + (size_t)bz * M * NSEQ;
    #pragma unroll
    for (int mi = 0; mi < MI; ++mi)
      #pragma unroll
      for (int nj = 0; nj < 4; ++nj)
        #pragma unroll
        for (int r = 0; r < 4; ++r) {
          int row = m0 + wm + mi * 16 + lg * 4 + r;
          int col = n0 + wn + nj * 16 + lr;
          Cp[(size_t)row * NSEQ + col] = f2bf(acc[mi][nj][r]);
        }
  } else {
    float* Cp = Cf + (size_t)bz * M * NSEQ;
    #pragma unroll
    for (int mi = 0; mi < MI; ++mi)
      #pragma unroll
      for (int nj = 0; nj < 4; ++nj)
        #pragma unroll
        for (int r = 0; r < 4; ++r) {
          int row = m0 + wm + mi * 16 + lg * 4 + r;
          int col = n0 + wn + nj * 16 + lr;
          Cp[(size_t)row * NSEQ + col] = acc[mi][nj][r] + bias[row];
        }
  }
}

// ---------------- RoPE for K only: qkv rows 1024..2047 -> Kt [b][h][n][64] bf16 ----------------
__global__ void k_ropeK(const short* __restrict__ qkv, const float* __restrict__ tab,
                        short* __restrict__ Kt) {
  __shared__ short lt[64 * 64];   // [n][d] swizzled: elem d stored at d ^ ((n&7)<<3)
  const int t = threadIdx.x;
  const int nc = blockIdx.x, h = blockIdx.y, b = blockIdx.z;
  const short* src = qkv + ((size_t)(b * O3 + INNER + h * 64)) * NSEQ + nc * 64;
  {
    int dl = t >> 2, q4 = t & 3;
    #pragma unroll
    for (int v = 0; v < 2; ++v) {
      bf16x8 x = *(const bf16x8*)(src + (size_t)dl * NSEQ + q4 * 16 + v * 8);
      #pragma unroll
      for (int e = 0; e < 8; ++e) {
        int n = q4 * 16 + v * 8 + e;
        lt[n * 64 + (dl ^ ((n & 7) << 3))] = x[e];
      }
    }
  }
  __syncthreads();
  const int dseg = t & 7;
  #pragma unroll
  for (int itn = 0; itn < 2; ++itn) {
    int n = (t >> 3) + itn * 32;
    int gn = nc * 64 + n;
    bf16x8 v0 = *(const bf16x8*)&lt[n * 64 + ((dseg ^ (n & 7)) << 3)];
    bf16x8 vp = *(const bf16x8*)&lt[n * 64 + (((dseg ^ 4) ^ (n & 7)) << 3)];
    const float* tb = tab + (size_t)gn * 64 + (dseg & 3) * 8;
    float sgn = (dseg < 4) ? -1.0f : 1.0f;
    bf16x8 outv;
    #pragma unroll
    for (int e = 0; e < 8; ++e) {
      float c = tb[e], s = tb[32 + e];
      outv[e] = f2bf(bf2f(v0[e]) * c + sgn * bf2f(vp[e]) * s);
    }
    *(bf16x8*)(Kt + (((size_t)(b * HEADS + h)) * NSEQ + gn) * 64 + dseg * 8) = outv;
  }
}

// ---------------- flash attention (fixed-shift softmax, swapped QK^T -> packed b64 P-writes) ----------------
// 256 thr = 4 waves; wave owns 32 q-rows (2 sub-tiles of 16); block = 128 q-rows.
// S computed as mfma(K_frag, Q_frag): D[m=j][n=i] -> lane holds P[i=lr][j=16jg+4lg+r],
// 4 consecutive j per reg quad -> one ds_write_b64 per (sub,jg). P layout [16 i][64 j] swizzled.
__global__ __launch_bounds__(256) void k_attn(const short* __restrict__ qkv,
                                              const short* __restrict__ Kt,
                                              const float* __restrict__ tab,
                                              short* __restrict__ AOt) {
  __shared__ __align__(16) short smem[16384];   // 32 KiB
  const int t = threadIdx.x, lane = t & 63, w = t >> 6;
  const int lr = lane & 15, lg = lane >> 4;
  const int L = ((blockIdx.x & 7) << 6) | (blockIdx.x >> 3);
  const int it = L & 15, h = (L >> 4) & 15, b = L >> 8;
  const int i0 = it * 128;

  // ---- Q stage: qkv rows h*64..+63 (o-major) -> smem[0..8192) as [64 d][128 n] swizzled
  const short* Qsrc = qkv + ((size_t)(b * O3 + h * 64)) * NSEQ;
  {
    int dl = t >> 2, q4 = t & 3;
    const short* gq = Qsrc + (size_t)dl * NSEQ + i0 + q4 * 32;
    #pragma unroll
    for (int kk = 0; kk < 4; ++kk) {
      bf16x8 x = *(const bf16x8*)(gq + kk * 8);
      *(bf16x8*)&smem[dl * 128 + (((q4 * 4 + kk) ^ (dl & 7)) << 3)] = x;
    }
  }
  __syncthreads();
  // ---- gather + RoPE + 0.125 scale -> aq[sub][part]
  bf16x8 aq[2][2];
  #pragma unroll
  for (int sub = 0; sub < 2; ++sub) {
    int il = w * 32 + sub * 16 + lr;
    int gn = i0 + il;
    float q0[8], q1[8];
    #pragma unroll
    for (int e = 0; e < 8; ++e) {
      int d0 = lg * 8 + e;
      int sw = (((il >> 3) ^ e) << 3) + (il & 7);
      q0[e] = bf2f(smem[d0 * 128 + sw]);
      q1[e] = bf2f(smem[(d0 + 32) * 128 + sw]);
    }
    const float* tb = tab + (size_t)gn * 64 + lg * 8;
    bf16x8 a0, a1;
    #pragma unroll
    for (int e = 0; e < 8; ++e) {
      float c = tb[e], s = tb[32 + e];
      a0[e] = f2bf((q0[e] * c - q1[e] * s) * 0.125f);
      a1[e] = f2bf((q1[e] * c + q0[e] * s) * 0.125f);
    }
    aq[sub][0] = a0; aq[sub][1] = a1;
  }

  const short* Kh = Kt + ((size_t)(b * HEADS + h)) * NSEQ * 64;
  const short* Vh = qkv + ((size_t)(b * O3 + 2 * INNER + h * 64)) * NSEQ;
  short* lds_k = smem;                       // [64 j][64 d] swizzled
  short* lds_v = smem + 4096;                // [64 d][64 j] swizzled
  short* lds_p = smem + 8192 + w * 2048;     // per-wave: 2 subs x [16 i][64 j] swizzled

  f32x4 o_acc[2][4];
  f32x4 sum_acc[2];
  const f32x4 zf = {0.f, 0.f, 0.f, 0.f};
  const f32x4 c10 = {-10.f, -10.f, -10.f, -10.f};
  #pragma unroll
  for (int sub = 0; sub < 2; ++sub) {
    sum_acc[sub] = zf;
    #pragma unroll
    for (int dg = 0; dg < 4; ++dg) o_acc[sub][dg] = zf;
  }
  bf16x8 ones;
  #pragma unroll
  for (int e = 0; e < 8; ++e) ones[e] = (short)0x3F80;

  const int srow = t >> 3, sslot = t & 7;
  const short* gk0 = Kh + (size_t)srow * 64 + sslot * 8;
  const short* gk1 = gk0 + 32 * 64;
  const short* gv0 = Vh + (size_t)srow * NSEQ + sslot * 8;
  const short* gv1 = gv0 + (size_t)32 * NSEQ;
  const int sk0 = srow * 64 + ((sslot ^ (srow & 7)) << 3);

  bf16x8 rk0 = *(const bf16x8*)gk0, rk1 = *(const bf16x8*)gk1;
  bf16x8 rv0 = *(const bf16x8*)gv0, rv1 = *(const bf16x8*)gv1;

  for (int jt = 0; jt < NSEQ / 64; ++jt) {
    __syncthreads();
    *(bf16x8*)&lds_k[sk0] = rk0; *(bf16x8*)&lds_k[sk0 + 2048] = rk1;
    *(bf16x8*)&lds_v[sk0] = rv0; *(bf16x8*)&lds_v[sk0 + 2048] = rv1;
    __syncthreads();
    if (jt + 1 < NSEQ / 64) {
      gk0 += 64 * 64; gk1 += 64 * 64; gv0 += 64; gv1 += 64;
      rk0 = *(const bf16x8*)gk0; rk1 = *(const bf16x8*)gk1;
      rv0 = *(const bf16x8*)gv0; rv1 = *(const bf16x8*)gv1;
    }
    // ---- S^T tiles: mfma(K,Q) -> D[m=j][n=i]; K-frag/Q-frag identical bytes to un-swapped form
    f32x4 sA[4], sB[4];
    __builtin_amdgcn_s_setprio(1);
    #pragma unroll
    for (int jg = 0; jg < 4; ++jg) {
      int row = jg * 16 + lr;
      bf16x8 bk0 = *(const bf16x8*)&lds_k[row * 64 + ((lg ^ (row & 7)) << 3)];
      bf16x8 bk1 = *(const bf16x8*)&lds_k[row * 64 + (((4 + lg) ^ (row & 7)) << 3)];
      sA[jg] = __builtin_amdgcn_mfma_f32_16x16x32_bf16(bk0, aq[0][0], c10, 0, 0, 0);
      sA[jg] = __builtin_amdgcn_mfma_f32_16x16x32_bf16(bk1, aq[0][1], sA[jg], 0, 0, 0);
      sB[jg] = __builtin_amdgcn_mfma_f32_16x16x32_bf16(bk0, aq[1][0], c10, 0, 0, 0);
      sB[jg] = __builtin_amdgcn_mfma_f32_16x16x32_bf16(bk1, aq[1][1], sB[jg], 0, 0, 0);
    }
    __builtin_amdgcn_s_setprio(0);
    // ---- per sub: p = exp(s), pack 4 consecutive j -> ds_write_b64; then sum + PV
    bf16x8 bv[2][4];
    #pragma unroll
    for (int sub = 0; sub < 2; ++sub) {
      short* pb = lds_p + sub * 1024;
      #pragma unroll
      for (int jg = 0; jg < 4; ++jg) {
        const f32x4& s4 = sub ? sB[jg] : sA[jg];
        unsigned long long pk =
            (unsigned long long)(unsigned short)f2bf(__expf(s4[0]))
          | ((unsigned long long)(unsigned short)f2bf(__expf(s4[1])) << 16)
          | ((unsigned long long)(unsigned short)f2bf(__expf(s4[2])) << 32)
          | ((unsigned long long)(unsigned short)f2bf(__expf(s4[3])) << 48);
        // i = lr ; j0 = 16*jg + 4*lg ; slot s = j0>>3 = 2jg + (lg>>1) ; within-slot 4*(lg&1)
        int sslt = 2 * jg + (lg >> 1);
        *(unsigned long long*)&pb[lr * 64 + (((sslt) ^ (lr & 7)) << 3) + 4 * (lg & 1)] = pk;
      }
      #pragma unroll
      for (int jj = 0; jj < 2; ++jj) {
        bf16x8 ap = *(const bf16x8*)&pb[lr * 64 + (((jj * 4 + lg) ^ (lr & 7)) << 3)];
        sum_acc[sub] = __builtin_amdgcn_mfma_f32_16x16x32_bf16(ones, ap, sum_acc[sub], 0, 0, 0);
        if (sub == 0) {
          #pragma unroll
          for (int dg = 0; dg < 4; ++dg) {
            int row = dg * 16 + lr;
            bv[jj][dg] = *(const bf16x8*)&lds_v[row * 64 + (((jj * 4 + lg) ^ (row & 7)) << 3)];
          }
        }
        __builtin_amdgcn_s_setprio(1);
        #pragma unroll
        for (int dg = 0; dg < 4; ++dg)
          o_acc[sub][dg] = __builtin_amdgcn_mfma_f32_16x16x32_bf16(ap, bv[jj][dg], o_acc[sub][dg], 0, 0, 0);
        __builtin_amdgcn_s_setprio(0);
      }
    }
  }
  // ---- epilogue: O /= l ; AOt[b][n][h*64+d]
  short* Op = AOt + (size_t)b * NSEQ * INNER;
  #pragma unroll
  for (int sub = 0; sub < 2; ++sub) {
    float l0 = sum_acc[sub][0];
    float inv[4];
    #pragma unroll
    for (int r = 0; r < 4; ++r) inv[r] = 1.0f / __shfl(l0, 4 * lg + r, 64);
    #pragma unroll
    for (int dg = 0; dg < 4; ++dg)
      #pragma unroll
      for (int r = 0; r < 4; ++r) {
        int n = i0 + w * 32 + sub * 16 + 4 * lg + r;
        int c = h * 64 + dg * 16 + lr;
        Op[(size_t)n * INNER + c] = f2bf(o_acc[sub][dg][r] * inv[r]);
      }
  }
}

// ---------------- launch ----------------
extern "C" void kernel_launch(void* const* d_in, const int* in_sizes, int n_in,
                              void* d_out, int out_size, void* d_ws, size_t ws_size,
                              hipStream_t stream) {
  const float* x = (const float*)d_in[0];
  const float* w_qkv = (const float*)d_in[1];
  const float* w_out = (const float*)d_in[2];
  const float* b_out = (const float*)d_in[3];
  float* out = (float*)d_out;
  char* ws = (char*)d_ws;
  short* wq_bf = (short*)(ws + 0);          //  6,291,456
  short* wo_bf = (short*)(ws + 6291456);    //  2,097,152
  short* Xt    = (short*)(ws + 8388608);    //  8,388,608  [b][n][d] bf16
  float* tab   = (float*)(ws + 16777216);   //    524,288  [2048 n][64] cos|sin
  short* qkv   = (short*)(ws + 17301504);   // 25,165,824  [b][3072][n] bf16
  short* Kt    = (short*)(ws + 42467328);   //  8,388,608  [b][h][n][64] bf16 (rope'd)
  short* AOt   = (short*)(ws + 50855936);   //  8,388,608  [b][n][1024] bf16

  k_cast_weights<<<4096, 256, 0, stream>>>(w_qkv, w_out, wq_bf, wo_bf);
  k_rope_table<<<256, 256, 0, stream>>>(tab);
  k_transpose_x<<<dim3(32, 16, BATCH), 256, 0, stream>>>(x, Xt);
  k_gemm<0, 128><<<768, 256, 0, stream>>>(wq_bf, Xt, qkv, nullptr, nullptr, O3, DIM);
  k_ropeK<<<dim3(32, 16, BATCH), 256, 0, stream>>>(qkv, tab, Kt);
  k_attn<<<512, 256, 0, stream>>>(qkv, Kt, tab, AOt);
  k_gemm<1, 64><<<512, 256, 0, stream>>>(wo_bf, AOt, nullptr, out, b_out, INNER, INNER);
}

// Round 9
// 198.771 us; speedup vs baseline: 1.0235x; 1.0050x over previous
//
#include <hip/hip_runtime.h>
#include <stdint.h>

#define BATCH 2
#define DIM 1024
#define NSEQ 2048
#define HEADS 16
#define DHEAD 64
#define INNER 1024
#define O3 3072

typedef __attribute__((ext_vector_type(8))) short bf16x8;
typedef __attribute__((ext_vector_type(4))) float f32x4;

typedef __attribute__((address_space(3))) unsigned int* as3u;
typedef const __attribute__((address_space(1))) unsigned int* as1u;

__device__ __forceinline__ short f2bf(float f) {
  unsigned int u = __builtin_bit_cast(unsigned int, f);
  unsigned int r = (u + 0x7fffu + ((u >> 16) & 1u)) >> 16;
  return (short)(unsigned short)r;
}
__device__ __forceinline__ float bf2f(short s) {
  unsigned int u = ((unsigned int)(unsigned short)s) << 16;
  return __builtin_bit_cast(float, u);
}
__device__ __forceinline__ void gload16(const short* g, short* l) {
  __builtin_amdgcn_global_load_lds((as1u)(const void*)g, (as3u)(void*)l, 16, 0, 0);
}

// ---------------- cast weights f32 -> bf16 ----------------
__global__ void k_cast_weights(const float* __restrict__ wq, const float* __restrict__ wo,
                               short* __restrict__ wq_bf, short* __restrict__ wo_bf) {
  int i = blockIdx.x * 256 + threadIdx.x;   // each thread: 4 elems
  const int NQ4 = O3 * DIM / 4;             // 786432
  const float4* src;
  unsigned int* dst;
  int j;
  if (i < NQ4) { src = (const float4*)wq; dst = (unsigned int*)wq_bf; j = i; }
  else         { src = (const float4*)wo; dst = (unsigned int*)wo_bf; j = i - NQ4; }
  float4 v = src[j];
  unsigned int lo = ((unsigned int)(unsigned short)f2bf(v.y) << 16) | (unsigned short)f2bf(v.x);
  unsigned int hi = ((unsigned int)(unsigned short)f2bf(v.w) << 16) | (unsigned short)f2bf(v.z);
  dst[j * 2] = lo;
  dst[j * 2 + 1] = hi;
}

// ---------------- rope table [n][64] f32: cols 0..31 = cos, 32..63 = sin ----------------
__global__ void k_rope_table(float* __restrict__ tab) {
  int i = blockIdx.x * 256 + threadIdx.x;   // 2048*32 = 65536
  int n = i >> 5, d = i & 31;
  float inv = powf(10000.0f, -(float)d * (1.0f / 32.0f));
  float ang = inv * (4.0f * (float)n);      // t = n * (8192/2048)
  float s, c;
  sincosf(ang, &s, &c);
  tab[n * 64 + d] = c;
  tab[n * 64 + 32 + d] = s;
}

// ---------------- x [b][d][n] f32 -> Xt [b][n][d] bf16 ----------------
__global__ void k_transpose_x(const float* __restrict__ x, short* __restrict__ xt) {
  __shared__ short tile[64 * 65];
  int nt = blockIdx.x, dt = blockIdx.y, b = blockIdx.z;
  int t = threadIdx.x;
  int tc = t & 63, tr = t >> 6;
  const float* xp = x + ((size_t)b * DIM + dt * 64) * NSEQ + nt * 64;
  #pragma unroll
  for (int r = 0; r < 16; ++r) {
    int d = r * 4 + tr;
    tile[d * 65 + tc] = f2bf(xp[(size_t)d * NSEQ + tc]);
  }
  __syncthreads();
  short* op = xt + ((size_t)b * NSEQ + nt * 64) * DIM + dt * 64;
  #pragma unroll
  for (int r = 0; r < 16; ++r) {
    int n = r * 4 + tr;
    op[(size_t)n * DIM + tc] = tile[tc * 65 + n];
  }
}

// ---------------- GEMM (2-phase dbuf, global_load_lds w16): C[M][2048] = A[M][K] * B^T ----------------
// B is [2048 rows][K] k-fastest. Grid: 1D NB = 16 * (M/BM) * BATCH, XCD-swizzled.
template <int EPI, int BM>
__global__ __launch_bounds__(256) void k_gemm(const short* __restrict__ A,
                                              const short* __restrict__ Bmat,
                                              short* __restrict__ Cbf, float* __restrict__ Cf,
                                              const float* __restrict__ bias, int M, int K) {
  constexpr int MI = BM / 32;               // m-fragments per wave (128->4, 64->2)
  __shared__ __align__(16) short lds_a[2][BM * 32];
  __shared__ __align__(16) short lds_b[2][128 * 32];
  const int t = threadIdx.x;
  const int lane = t & 63, w = t >> 6;
  const int lr = lane & 15, lg = lane >> 4;
  // XCD-chunked bijective swizzle (gridDim.x % 8 == 0)
  const int cpx = gridDim.x >> 3;
  const int swz = (blockIdx.x & 7) * cpx + (blockIdx.x >> 3);
  const int mtiles = M / BM;
  const int n0 = (swz & 15) * 128;
  const int rest = swz >> 4;
  const int m0 = (rest % mtiles) * BM;
  const int bz = rest / mtiles;

  const short* Bp = Bmat + (size_t)bz * NSEQ * K;
  const int arow0 = (BM == 128 ? 32 * w : 16 * w);
  const short* gA = A + (size_t)(m0 + arow0 + (lane >> 2)) * K + (lane & 3) * 8;
  const short* gB = Bp + (size_t)(n0 + 32 * w + (lane >> 2)) * K + (lane & 3) * 8;
  const int wm = (w >> 1) * (BM / 2), wn = (w & 1) * 64;

  auto STAGE = [&](int buf, int kk) {
    const short* ga = gA + kk * 32;
    const short* gb = gB + kk * 32;
    gload16(ga, &lds_a[buf][arow0 * 32]);
    if (BM == 128) gload16(ga + (size_t)16 * K, &lds_a[buf][(arow0 + 16) * 32]);
    gload16(gb, &lds_b[buf][(32 * w) * 32]);
    gload16(gb + (size_t)16 * K, &lds_b[buf][(32 * w + 16) * 32]);
  };

  f32x4 acc[MI][4];
  const f32x4 zf = {0.f, 0.f, 0.f, 0.f};
  #pragma unroll
  for (int i = 0; i < MI; ++i)
    #pragma unroll
    for (int j = 0; j < 4; ++j) acc[i][j] = zf;

  STAGE(0, 0);
  asm volatile("s_waitcnt vmcnt(0)" ::: "memory");
  __syncthreads();

  const int nkt = K >> 5;
  int cur = 0;
  for (int kt = 0; kt < nkt; ++kt) {
    if (kt + 1 < nkt) STAGE(cur ^ 1, kt + 1);
    bf16x8 af[MI], bfr[4];
    #pragma unroll
    for (int mi = 0; mi < MI; ++mi)
      af[mi] = *(const bf16x8*)&lds_a[cur][(wm + mi * 16 + lr) * 32 + lg * 8];
    #pragma unroll
    for (int nj = 0; nj < 4; ++nj)
      bfr[nj] = *(const bf16x8*)&lds_b[cur][(wn + nj * 16 + lr) * 32 + lg * 8];
    __builtin_amdgcn_s_setprio(1);
    #pragma unroll
    for (int mi = 0; mi < MI; ++mi)
      #pragma unroll
      for (int nj = 0; nj < 4; ++nj)
        acc[mi][nj] = __builtin_amdgcn_mfma_f32_16x16x32_bf16(af[mi], bfr[nj], acc[mi][nj], 0, 0, 0);
    __builtin_amdgcn_s_setprio(0);
    asm volatile("s_waitcnt vmcnt(0)" ::: "memory");
    __syncthreads();
    cur ^= 1;
  }

  if (EPI == 0) {
    short* Cp = Cbf + (size_t)bz * M * NSEQ;
    #pragma unroll
    for (int mi = 0; mi < MI; ++mi)
      #pragma unroll
      for (int nj = 0; nj < 4; ++nj)
        #pragma unroll
        for (int r = 0; r < 4; ++r) {
          int row = m0 + wm + mi * 16 + lg * 4 + r;
          int col = n0 + wn + nj * 16 + lr;
          Cp[(size_t)row * NSEQ + col] = f2bf(acc[mi][nj][r]);
        }
  } else {
    float* Cp = Cf + (size_t)bz * M * NSEQ;
    #pragma unroll
    for (int mi = 0; mi < MI; ++mi)
      #pragma unroll
      for (int nj = 0; nj < 4; ++nj)
        #pragma unroll
        for (int r = 0; r < 4; ++r) {
          int row = m0 + wm + mi * 16 + lg * 4 + r;
          int col = n0 + wn + nj * 16 + lr;
          Cp[(size_t)row * NSEQ + col] = acc[mi][nj][r] + bias[row];
        }
  }
}

// ---------------- RoPE for K only: qkv rows 1024..2047 -> Kt [b][h][n][64] bf16 ----------------
__global__ void k_ropeK(const short* __restrict__ qkv, const float* __restrict__ tab,
                        short* __restrict__ Kt) {
  __shared__ short lt[64 * 64];   // [n][d] swizzled: elem d stored at d ^ ((n&7)<<3)
  const int t = threadIdx.x;
  const int nc = blockIdx.x, h = blockIdx.y, b = blockIdx.z;
  const short* src = qkv + ((size_t)(b * O3 + INNER + h * 64)) * NSEQ + nc * 64;
  {
    int dl = t >> 2, q4 = t & 3;
    #pragma unroll
    for (int v = 0; v < 2; ++v) {
      bf16x8 x = *(const bf16x8*)(src + (size_t)dl * NSEQ + q4 * 16 + v * 8);
      #pragma unroll
      for (int e = 0; e < 8; ++e) {
        int n = q4 * 16 + v * 8 + e;
        lt[n * 64 + (dl ^ ((n & 7) << 3))] = x[e];
      }
    }
  }
  __syncthreads();
  const int dseg = t & 7;
  #pragma unroll
  for (int itn = 0; itn < 2; ++itn) {
    int n = (t >> 3) + itn * 32;
    int gn = nc * 64 + n;
    bf16x8 v0 = *(const bf16x8*)&lt[n * 64 + ((dseg ^ (n & 7)) << 3)];
    bf16x8 vp = *(const bf16x8*)&lt[n * 64 + (((dseg ^ 4) ^ (n & 7)) << 3)];
    const float* tb = tab + (size_t)gn * 64 + (dseg & 3) * 8;
    float sgn = (dseg < 4) ? -1.0f : 1.0f;
    bf16x8 outv;
    #pragma unroll
    for (int e = 0; e < 8; ++e) {
      float c = tb[e], s = tb[32 + e];
      outv[e] = f2bf(bf2f(v0[e]) * c + sgn * bf2f(vp[e]) * s);
    }
    *(bf16x8*)(Kt + (((size_t)(b * HEADS + h)) * NSEQ + gn) * 64 + dseg * 8) = outv;
  }
}

// ---------------- flash attention ----------------
// Fixed-shift softmax in exp2 domain: Q pre-scaled by 0.125*log2e, C-init = -10*log2e,
// p = exp2(s) = e^(raw_s - 10) (bare v_exp_f32, no per-value mul).
// Swapped QK^T (mfma(K,Q)) -> lane holds P[i=lr][j=16jg+4lg+r]; manual shift-pack -> one
// ds_write_b64 per jg (round-7-verified path; NO cvt_pk). Row-sum via ones-MFMA.
__global__ __launch_bounds__(256) void k_attn(const short* __restrict__ qkv,
                                              const short* __restrict__ Kt,
                                              const float* __restrict__ tab,
                                              short* __restrict__ AOt) {
  __shared__ __align__(16) short smem[16384];   // 32 KiB
  const int t = threadIdx.x, lane = t & 63, w = t >> 6;
  const int lr = lane & 15, lg = lane >> 4;
  const int L = ((blockIdx.x & 7) << 6) | (blockIdx.x >> 3);
  const int it = L & 15, h = (L >> 4) & 15, b = L >> 8;
  const int i0 = it * 128;
  const float QSCALE = 0.125f * 1.4426950408889634f;   // fold log2e into Q

  // ---- Q stage: qkv rows h*64..+63 (o-major) -> smem[0..8192) as [64 d][128 n] swizzled
  const short* Qsrc = qkv + ((size_t)(b * O3 + h * 64)) * NSEQ;
  {
    int dl = t >> 2, q4 = t & 3;
    const short* gq = Qsrc + (size_t)dl * NSEQ + i0 + q4 * 32;
    #pragma unroll
    for (int kk = 0; kk < 4; ++kk) {
      bf16x8 x = *(const bf16x8*)(gq + kk * 8);
      *(bf16x8*)&smem[dl * 128 + (((q4 * 4 + kk) ^ (dl & 7)) << 3)] = x;
    }
  }
  __syncthreads();
  // ---- gather + RoPE + QSCALE -> aq[sub][part]
  bf16x8 aq[2][2];
  #pragma unroll
  for (int sub = 0; sub < 2; ++sub) {
    int il = w * 32 + sub * 16 + lr;
    int gn = i0 + il;
    float q0[8], q1[8];
    #pragma unroll
    for (int e = 0; e < 8; ++e) {
      int d0 = lg * 8 + e;
      int sw = (((il >> 3) ^ e) << 3) + (il & 7);
      q0[e] = bf2f(smem[d0 * 128 + sw]);
      q1[e] = bf2f(smem[(d0 + 32) * 128 + sw]);
    }
    const float* tb = tab + (size_t)gn * 64 + lg * 8;
    bf16x8 a0, a1;
    #pragma unroll
    for (int e = 0; e < 8; ++e) {
      float c = tb[e], s = tb[32 + e];
      a0[e] = f2bf((q0[e] * c - q1[e] * s) * QSCALE);
      a1[e] = f2bf((q1[e] * c + q0[e] * s) * QSCALE);
    }
    aq[sub][0] = a0; aq[sub][1] = a1;
  }

  const short* Kh = Kt + ((size_t)(b * HEADS + h)) * NSEQ * 64;
  const short* Vh = qkv + ((size_t)(b * O3 + 2 * INNER + h * 64)) * NSEQ;
  short* lds_k = smem;                       // [64 j][64 d] swizzled
  short* lds_v = smem + 4096;                // [64 d][64 j] swizzled
  short* lds_p = smem + 8192 + w * 2048;     // per-wave: 2 subs x [16 i][64 j] swizzled

  f32x4 o_acc[2][4];
  f32x4 sum_acc[2];
  const f32x4 zf = {0.f, 0.f, 0.f, 0.f};
  const f32x4 cinit = {-14.426950408889634f, -14.426950408889634f,
                       -14.426950408889634f, -14.426950408889634f};
  #pragma unroll
  for (int sub = 0; sub < 2; ++sub) {
    sum_acc[sub] = zf;
    #pragma unroll
    for (int dg = 0; dg < 4; ++dg) o_acc[sub][dg] = zf;
  }
  bf16x8 ones;
  #pragma unroll
  for (int e = 0; e < 8; ++e) ones[e] = (short)0x3F80;

  const int srow = t >> 3, sslot = t & 7;
  const short* gk0 = Kh + (size_t)srow * 64 + sslot * 8;
  const short* gk1 = gk0 + 32 * 64;
  const short* gv0 = Vh + (size_t)srow * NSEQ + sslot * 8;
  const short* gv1 = gv0 + (size_t)32 * NSEQ;
  const int sk0 = srow * 64 + ((sslot ^ (srow & 7)) << 3);

  bf16x8 rk0 = *(const bf16x8*)gk0, rk1 = *(const bf16x8*)gk1;
  bf16x8 rv0 = *(const bf16x8*)gv0, rv1 = *(const bf16x8*)gv1;

  for (int jt = 0; jt < NSEQ / 64; ++jt) {
    __syncthreads();
    *(bf16x8*)&lds_k[sk0] = rk0; *(bf16x8*)&lds_k[sk0 + 2048] = rk1;
    *(bf16x8*)&lds_v[sk0] = rv0; *(bf16x8*)&lds_v[sk0 + 2048] = rv1;
    __syncthreads();
    if (jt + 1 < NSEQ / 64) {
      gk0 += 64 * 64; gk1 += 64 * 64; gv0 += 64; gv1 += 64;
      rk0 = *(const bf16x8*)gk0; rk1 = *(const bf16x8*)gk1;
      rv0 = *(const bf16x8*)gv0; rv1 = *(const bf16x8*)gv1;
    }
    // ---- S^T tiles: mfma(K,Q) -> D[m=j][n=i]; C-init = -10*log2e
    f32x4 sA[4], sB[4];
    __builtin_amdgcn_s_setprio(1);
    #pragma unroll
    for (int jg = 0; jg < 4; ++jg) {
      int row = jg * 16 + lr;
      bf16x8 bk0 = *(const bf16x8*)&lds_k[row * 64 + ((lg ^ (row & 7)) << 3)];
      bf16x8 bk1 = *(const bf16x8*)&lds_k[row * 64 + (((4 + lg) ^ (row & 7)) << 3)];
      sA[jg] = __builtin_amdgcn_mfma_f32_16x16x32_bf16(bk0, aq[0][0], cinit, 0, 0, 0);
      sA[jg] = __builtin_amdgcn_mfma_f32_16x16x32_bf16(bk1, aq[0][1], sA[jg], 0, 0, 0);
      sB[jg] = __builtin_amdgcn_mfma_f32_16x16x32_bf16(bk0, aq[1][0], cinit, 0, 0, 0);
      sB[jg] = __builtin_amdgcn_mfma_f32_16x16x32_bf16(bk1, aq[1][1], sB[jg], 0, 0, 0);
    }
    __builtin_amdgcn_s_setprio(0);
    // ---- per sub: p = exp2(s) (bare v_exp_f32); manual pack -> one b64 write per jg
    bf16x8 bv[2][4];
    #pragma unroll
    for (int sub = 0; sub < 2; ++sub) {
      short* pb = lds_p + sub * 1024;
      #pragma unroll
      for (int jg = 0; jg < 4; ++jg) {
        const f32x4& s4 = sub ? sB[jg] : sA[jg];
        float p0 = __builtin_amdgcn_exp2f(s4[0]);
        float p1 = __builtin_amdgcn_exp2f(s4[1]);
        float p2 = __builtin_amdgcn_exp2f(s4[2]);
        float p3 = __builtin_amdgcn_exp2f(s4[3]);
        unsigned long long pk =
            (unsigned long long)(unsigned short)f2bf(p0)
          | ((unsigned long long)(unsigned short)f2bf(p1) << 16)
          | ((unsigned long long)(unsigned short)f2bf(p2) << 32)
          | ((unsigned long long)(unsigned short)f2bf(p3) << 48);
        // i = lr ; j0 = 16*jg + 4*lg ; slot = 2jg + (lg>>1) ; within-slot 4*(lg&1)
        int sslt = 2 * jg + (lg >> 1);
        *(unsigned long long*)&pb[lr * 64 + ((sslt ^ (lr & 7)) << 3) + 4 * (lg & 1)] = pk;
      }
      #pragma unroll
      for (int jj = 0; jj < 2; ++jj) {
        bf16x8 ap = *(const bf16x8*)&pb[lr * 64 + (((jj * 4 + lg) ^ (lr & 7)) << 3)];
        sum_acc[sub] = __builtin_amdgcn_mfma_f32_16x16x32_bf16(ones, ap, sum_acc[sub], 0, 0, 0);
        if (sub == 0) {
          #pragma unroll
          for (int dg = 0; dg < 4; ++dg) {
            int row = dg * 16 + lr;
            bv[jj][dg] = *(const bf16x8*)&lds_v[row * 64 + (((jj * 4 + lg) ^ (row & 7)) << 3)];
          }
        }
        __builtin_amdgcn_s_setprio(1);
        #pragma unroll
        for (int dg = 0; dg < 4; ++dg)
          o_acc[sub][dg] = __builtin_amdgcn_mfma_f32_16x16x32_bf16(ap, bv[jj][dg], o_acc[sub][dg], 0, 0, 0);
        __builtin_amdgcn_s_setprio(0);
      }
    }
  }
  // ---- epilogue: O /= l ; AOt[b][n][h*64+d]
  short* Op = AOt + (size_t)b * NSEQ * INNER;
  #pragma unroll
  for (int sub = 0; sub < 2; ++sub) {
    float l0 = sum_acc[sub][0];
    float inv[4];
    #pragma unroll
    for (int r = 0; r < 4; ++r) inv[r] = 1.0f / __shfl(l0, 4 * lg + r, 64);
    #pragma unroll
    for (int dg = 0; dg < 4; ++dg)
      #pragma unroll
      for (int r = 0; r < 4; ++r) {
        int n = i0 + w * 32 + sub * 16 + 4 * lg + r;
        int c = h * 64 + dg * 16 + lr;
        Op[(size_t)n * INNER + c] = f2bf(o_acc[sub][dg][r] * inv[r]);
      }
  }
}

// ---------------- launch ----------------
extern "C" void kernel_launch(void* const* d_in, const int* in_sizes, int n_in,
                              void* d_out, int out_size, void* d_ws, size_t ws_size,
                              hipStream_t stream) {
  const float* x = (const float*)d_in[0];
  const float* w_qkv = (const float*)d_in[1];
  const float* w_out = (const float*)d_in[2];
  const float* b_out = (const float*)d_in[3];
  float* out = (float*)d_out;
  char* ws = (char*)d_ws;
  short* wq_bf = (short*)(ws + 0);          //  6,291,456
  short* wo_bf = (short*)(ws + 6291456);    //  2,097,152
  short* Xt    = (short*)(ws + 8388608);    //  8,388,608  [b][n][d] bf16
  float* tab   = (float*)(ws + 16777216);   //    524,288  [2048 n][64] cos|sin
  short* qkv   = (short*)(ws + 17301504);   // 25,165,824  [b][3072][n] bf16
  short* Kt    = (short*)(ws + 42467328);   //  8,388,608  [b][h][n][64] bf16 (rope'd)
  short* AOt   = (short*)(ws + 50855936);   //  8,388,608  [b][n][1024] bf16

  k_cast_weights<<<4096, 256, 0, stream>>>(w_qkv, w_out, wq_bf, wo_bf);
  k_rope_table<<<256, 256, 0, stream>>>(tab);
  k_transpose_x<<<dim3(32, 16, BATCH), 256, 0, stream>>>(x, Xt);
  k_gemm<0, 128><<<768, 256, 0, stream>>>(wq_bf, Xt, qkv, nullptr, nullptr, O3, DIM);
  k_ropeK<<<dim3(32, 16, BATCH), 256, 0, stream>>>(qkv, tab, Kt);
  k_attn<<<512, 256, 0, stream>>>(qkv, Kt, tab, AOt);
  k_gemm<1, 64><<<512, 256, 0, stream>>>(wo_bf, AOt, nullptr, out, b_out, INNER, INNER);
}